// Round 1
// baseline (3321.153 us; speedup 1.0000x reference)
//
#include <hip/hip_runtime.h>
#include <math.h>

#define S 512
#define D 1024
#define H 16
#define DH 64
#define L 2
#define DN 512
#define DE 256
#define KTOP 3
#define E (S*KTOP)
#define D3 (3*D)
#define DFF (4*D)
#define EK (2*D+1)

// ---------------- reduction helpers (block = 256 = 4 waves) ----------------
__device__ __forceinline__ float block_sum_256(float v, volatile float* sh) {
    int lane = threadIdx.x & 63, wid = threadIdx.x >> 6;
    #pragma unroll
    for (int o = 32; o > 0; o >>= 1) v += __shfl_down(v, o, 64);
    if (lane == 0) sh[wid] = v;
    __syncthreads();
    float r = sh[0] + sh[1] + sh[2] + sh[3];
    __syncthreads();
    return r;
}
__device__ __forceinline__ float block_max_256(float v, volatile float* sh) {
    int lane = threadIdx.x & 63, wid = threadIdx.x >> 6;
    #pragma unroll
    for (int o = 32; o > 0; o >>= 1) v = fmaxf(v, __shfl_down(v, o, 64));
    if (lane == 0) sh[wid] = v;
    __syncthreads();
    float r = fmaxf(fmaxf(sh[0], sh[1]), fmaxf(sh[2], sh[3]));
    __syncthreads();
    return r;
}

// ---------------- embedding + positional encoding ----------------
__global__ __launch_bounds__(256) void embed_kernel(
        const int* __restrict__ tok, const float* __restrict__ emb,
        const float* __restrict__ pe, float* __restrict__ x) {
    int s = blockIdx.x;
    int t = tok[s];
    for (int d = threadIdx.x; d < D; d += 256)
        x[(size_t)s*D + d] = emb[(size_t)t*D + d] + pe[(size_t)s*D + d];
}

// ---------------- generic C = A @ W^T + bias (optional exact GELU) ----------
// A: [M,Kd] row-major (lda=Kd), W: [N,Kd] row-major, C: [M,ldc] (writes N cols)
#define TM 64
#define TN 64
#define TK 16
__global__ __launch_bounds__(256) void gemm_bt(
        const float* __restrict__ A, const float* __restrict__ W,
        const float* __restrict__ bias, float* __restrict__ C,
        int M, int N, int Kd, int ldc, int act) {
    __shared__ float As[TK][TM];
    __shared__ float Ws[TK][TN];
    int bm = blockIdx.y * TM;
    int bn = blockIdx.x * TN;
    int tid = threadIdx.x;
    int tr = tid / 16;   // 0..15
    int tc = tid % 16;   // 0..15
    float acc[4][4] = {{0.f}};
    for (int k0 = 0; k0 < Kd; k0 += TK) {
        int r  = tid >> 2;          // 0..63
        int kb = (tid & 3) * 4;     // 0,4,8,12
        #pragma unroll
        for (int i = 0; i < 4; i++) {
            int kk = kb + i;
            float va = 0.f, vw = 0.f;
            if (bm + r < M && k0 + kk < Kd) va = A[(size_t)(bm + r)*Kd + k0 + kk];
            if (bn + r < N && k0 + kk < Kd) vw = W[(size_t)(bn + r)*Kd + k0 + kk];
            As[kk][r] = va;
            Ws[kk][r] = vw;
        }
        __syncthreads();
        #pragma unroll
        for (int kk = 0; kk < TK; kk++) {
            float a[4], b[4];
            #pragma unroll
            for (int i = 0; i < 4; i++) a[i] = As[kk][tr*4 + i];
            #pragma unroll
            for (int j = 0; j < 4; j++) b[j] = Ws[kk][tc*4 + j];
            #pragma unroll
            for (int i = 0; i < 4; i++)
                #pragma unroll
                for (int j = 0; j < 4; j++)
                    acc[i][j] += a[i] * b[j];
        }
        __syncthreads();
    }
    #pragma unroll
    for (int i = 0; i < 4; i++) {
        int m = bm + tr*4 + i;
        if (m >= M) continue;
        #pragma unroll
        for (int j = 0; j < 4; j++) {
            int n = bn + tc*4 + j;
            if (n >= N) continue;
            float v = acc[i][j] + (bias ? bias[n] : 0.f);
            if (act == 1)  // exact GELU: 0.5*x*(1+erf(x/sqrt(2)))
                v = 0.5f * v * (1.f + erff(v * 0.70710678118654752440f));
            C[(size_t)m*ldc + n] = v;
        }
    }
}

// ---------------- attention: scores = (q . k) / sqrt(DH) --------------------
// grid (S, H), block 256. w layout: [H, S, S]
__global__ __launch_bounds__(256) void attn_scores_kernel(
        const float* __restrict__ qkv, float* __restrict__ w) {
    int s = blockIdx.x, h = blockIdx.y;
    __shared__ float qrow[DH];
    if (threadIdx.x < DH)
        qrow[threadIdx.x] = qkv[(size_t)s*D3 + h*DH + threadIdx.x];
    __syncthreads();
    for (int t = threadIdx.x; t < S; t += 256) {
        const float* krow = &qkv[(size_t)t*D3 + D + h*DH];
        float acc = 0.f;
        #pragma unroll
        for (int d = 0; d < DH; d++) acc += qrow[d] * krow[d];
        w[((size_t)h*S + s)*S + t] = acc * 0.125f;  // 1/sqrt(64)
    }
}

// ---------------- softmax over last dim of w[h,s,:] -------------------------
__global__ __launch_bounds__(256) void softmax_kernel(float* __restrict__ w) {
    int s = blockIdx.x, h = blockIdx.y;
    float* row = w + ((size_t)h*S + s)*S;
    __shared__ float red[4];
    float lmax = -1e30f;
    for (int t = threadIdx.x; t < S; t += 256) lmax = fmaxf(lmax, row[t]);
    float m = block_max_256(lmax, red);
    float lsum = 0.f;
    for (int t = threadIdx.x; t < S; t += 256) {
        float e = expf(row[t] - m);
        row[t] = e;
        lsum += e;
    }
    float sum = block_sum_256(lsum, red);
    float inv = 1.f / sum;
    for (int t = threadIdx.x; t < S; t += 256) row[t] *= inv;
}

// ---------------- head average: avg[s,t] = mean_h w[h,s,t] ------------------
__global__ __launch_bounds__(256) void avg_heads_kernel(
        const float* __restrict__ w, float* __restrict__ avg) {
    size_t idx = (size_t)blockIdx.x * 256 + threadIdx.x;  // over S*S
    float acc = 0.f;
    #pragma unroll
    for (int h = 0; h < H; h++) acc += w[(size_t)h*S*S + idx];
    avg[idx] = acc * (1.f / H);
}

// ---------------- PV: out[s, h*DH+dh] = sum_t w[h,s,t] * v[t,h,dh] ----------
// grid (S/4, H), block 256: (s_local = tid/64, dh = tid%64)
__global__ __launch_bounds__(256) void attn_pv_kernel(
        const float* __restrict__ w, const float* __restrict__ qkv,
        float* __restrict__ out) {
    int h = blockIdx.y;
    int s = blockIdx.x * 4 + (threadIdx.x >> 6);
    int dh = threadIdx.x & 63;
    const float* wrow = &w[((size_t)h*S + s)*S];
    float acc = 0.f;
    for (int t = 0; t < S; t++)
        acc += wrow[t] * qkv[(size_t)t*D3 + 2*D + h*DH + dh];
    out[(size_t)s*D + h*DH + dh] = acc;
}

// ---------------- residual + LayerNorm (in-place on x), optional copy ------
__global__ __launch_bounds__(256) void add_ln_kernel(
        float* __restrict__ x, const float* __restrict__ y,
        const float* __restrict__ g, const float* __restrict__ b,
        float* __restrict__ copy_out) {
    int s = blockIdx.x;
    __shared__ float buf[D];
    __shared__ float red[4];
    float lsum = 0.f;
    for (int d = threadIdx.x; d < D; d += 256) {
        float t = x[(size_t)s*D + d] + y[(size_t)s*D + d];
        buf[d] = t;
        lsum += t;
    }
    float mean = block_sum_256(lsum, red) * (1.f / D);
    float lvar = 0.f;
    for (int d = threadIdx.x; d < D; d += 256) {
        float t = buf[d] - mean;
        lvar += t * t;
    }
    float var = block_sum_256(lvar, red) * (1.f / D);
    float inv = rsqrtf(var + 1e-5f);
    for (int d = threadIdx.x; d < D; d += 256) {
        float o = (buf[d] - mean) * inv * g[d] + b[d];
        x[(size_t)s*D + d] = o;
        if (copy_out) copy_out[(size_t)s*D + d] = o;
    }
}

// ---------------- top-K over masked last-layer avg attention ----------------
// strict > insertion == jax.lax.top_k (lower index wins ties)
__global__ __launch_bounds__(256) void topk_kernel(
        const float* __restrict__ avg_last, int* __restrict__ tgt,
        float* __restrict__ eidx_out) {
    int s = blockIdx.x * blockDim.x + threadIdx.x;
    if (s >= S) return;
    const float* row = avg_last + (size_t)s*S;
    float v0 = -1e30f, v1 = -1e30f, v2 = -1e30f;
    int i0 = 0, i1 = 0, i2 = 0;
    for (int t = 0; t < S; t++) {
        float v = (t == s) ? 0.f : row[t];   // final = avg * (1 - eye)
        if (v > v0)      { v2=v1; i2=i1; v1=v0; i1=i0; v0=v; i0=t; }
        else if (v > v1) { v2=v1; i2=i1; v1=v;  i1=t; }
        else if (v > v2) { v2=v;  i2=t; }
    }
    tgt[s*KTOP + 0] = i0; tgt[s*KTOP + 1] = i1; tgt[s*KTOP + 2] = i2;
    int idx[3] = {i0, i1, i2};
    for (int k = 0; k < KTOP; k++) {
        eidx_out[s*KTOP + k]      = (float)s;        // src row
        eidx_out[E + s*KTOP + k]  = (float)idx[k];   // tgt row
    }
}

// ---------------- edge_in = [e[src], e[tgt], attn[src,tgt]] -----------------
__global__ __launch_bounds__(256) void build_edge_in_kernel(
        const float* __restrict__ lo, const float* __restrict__ avg,
        const int* __restrict__ tgt, float* __restrict__ edge_in) {
    int e = blockIdx.x;
    int sn = e / KTOP;
    int tn = tgt[e];
    float a = avg[(size_t)sn*S + tn];
    for (int d = threadIdx.x; d < EK; d += 256) {
        float v;
        if (d < D)          v = lo[(size_t)sn*D + d];
        else if (d < 2*D)   v = lo[(size_t)tn*D + (d - D)];
        else                v = a;
        edge_in[(size_t)e*EK + d] = v;
    }
}

extern "C" void kernel_launch(void* const* d_in, const int* in_sizes, int n_in,
                              void* d_out, int out_size, void* d_ws, size_t ws_size,
                              hipStream_t stream) {
    const int*   token_ids = (const int*)  d_in[0];
    const float* emb       = (const float*)d_in[1];
    const float* pe        = (const float*)d_in[2];
    const float* in_proj_w = (const float*)d_in[3];
    const float* in_proj_b = (const float*)d_in[4];
    const float* out_w     = (const float*)d_in[5];
    const float* out_b     = (const float*)d_in[6];
    const float* ln1_w     = (const float*)d_in[7];
    const float* ln1_b     = (const float*)d_in[8];
    const float* ln2_w     = (const float*)d_in[9];
    const float* ln2_b     = (const float*)d_in[10];
    const float* ff1_w     = (const float*)d_in[11];
    const float* ff1_b     = (const float*)d_in[12];
    const float* ff2_w     = (const float*)d_in[13];
    const float* ff2_b     = (const float*)d_in[14];
    const float* node_w    = (const float*)d_in[15];
    const float* node_b    = (const float*)d_in[16];
    const float* edge_w    = (const float*)d_in[17];
    const float* edge_b    = (const float*)d_in[18];
    const float* comb_w    = (const float*)d_in[19];
    const float* comb_b    = (const float*)d_in[20];

    float* out = (float*)d_out;
    float* node_out = out;                       // [S, DN]
    float* edge_out = out + (size_t)S*DN;        // [E, DE]
    float* eidx_out = edge_out + (size_t)E*DE;   // [2, E] as floats

    // workspace layout (floats); ~60 MB total
    float* ws = (float*)d_ws;
    size_t off = 0;
    float* x       = ws + off; off += (size_t)S*D;      // current activations
    float* qkv     = ws + off; off += (size_t)S*D3;
    float* wfull   = ws + off; off += (size_t)H*S*S;    // per-layer attn probs
    float* avg     = ws + off; off += (size_t)L*S*S;    // head-averaged attn
    float* lo      = ws + off; off += (size_t)L*S*D;    // layer outputs
    float* att     = ws + off; off += (size_t)S*D;      // attention output
    float* ff      = ws + off; off += (size_t)S*DFF;    // ff1 activations
    float* tmp     = ws + off; off += (size_t)S*D;      // projection buffer
    float* edge_in = ws + off; off += (size_t)E*EK;
    float* feats   = ws + off; off += (size_t)E*(L*DE);
    int*   tgt     = (int*)(ws + off);                  // [E]

    dim3 blk(256);

    // x = emb[token_ids] + pe
    embed_kernel<<<S, blk, 0, stream>>>(token_ids, emb, pe, x);

    for (int i = 0; i < L; i++) {
        // qkv = x @ in_proj_w[i].T + in_proj_b[i]
        gemm_bt<<<dim3(D3/TN, S/TM), blk, 0, stream>>>(
            x, in_proj_w + (size_t)i*D3*D, in_proj_b + (size_t)i*D3,
            qkv, S, D3, D, D3, 0);
        // scores
        attn_scores_kernel<<<dim3(S, H), blk, 0, stream>>>(qkv, wfull);
        // softmax
        softmax_kernel<<<dim3(S, H), blk, 0, stream>>>(wfull);
        // head-average into avg[i]
        avg_heads_kernel<<<dim3(S*S/256), blk, 0, stream>>>(wfull, avg + (size_t)i*S*S);
        // attn_out = w @ v
        attn_pv_kernel<<<dim3(S/4, H), blk, 0, stream>>>(wfull, qkv, att);
        // out proj
        gemm_bt<<<dim3(D/TN, S/TM), blk, 0, stream>>>(
            att, out_w + (size_t)i*D*D, out_b + (size_t)i*D,
            tmp, S, D, D, D, 0);
        // x = LN(x + attn_proj)
        add_ln_kernel<<<S, blk, 0, stream>>>(
            x, tmp, ln1_w + (size_t)i*D, ln1_b + (size_t)i*D, nullptr);
        // ff1 + exact GELU
        gemm_bt<<<dim3(DFF/TN, S/TM), blk, 0, stream>>>(
            x, ff1_w + (size_t)i*DFF*D, ff1_b + (size_t)i*DFF,
            ff, S, DFF, D, DFF, 1);
        // ff2
        gemm_bt<<<dim3(D/TN, S/TM), blk, 0, stream>>>(
            ff, ff2_w + (size_t)i*D*DFF, ff2_b + (size_t)i*D,
            tmp, S, D, DFF, D, 0);
        // x = LN(x + ff) ; also save layer output
        add_ln_kernel<<<S, blk, 0, stream>>>(
            x, tmp, ln2_w + (size_t)i*D, ln2_b + (size_t)i*D, lo + (size_t)i*S*D);
    }

    // node_features = x @ node_w.T + node_b
    gemm_bt<<<dim3(DN/TN, S/TM), blk, 0, stream>>>(
        x, node_w, node_b, node_out, S, DN, D, DN, 0);

    // top-k over masked last-layer averaged attention; writes edge_index
    topk_kernel<<<dim3(2), blk, 0, stream>>>(avg + (size_t)(L-1)*S*S, tgt, eidx_out);

    // per-layer edge features
    for (int i = 0; i < L; i++) {
        build_edge_in_kernel<<<dim3(E), blk, 0, stream>>>(
            lo + (size_t)i*S*D, avg + (size_t)i*S*S, tgt, edge_in);
        gemm_bt<<<dim3(DE/TN, E/TM), blk, 0, stream>>>(
            edge_in, edge_w + (size_t)i*DE*EK, edge_b + (size_t)i*DE,
            feats + (size_t)i*DE, E, DE, EK, L*DE, 0);
    }

    // edge_features = feats @ comb_w.T + comb_b
    gemm_bt<<<dim3(DE/TN, E/TM), blk, 0, stream>>>(
        feats, comb_w, comb_b, edge_out, E, DE, L*DE, DE, 0);
}

// Round 3
// 2034.285 us; speedup vs baseline: 1.6326x; 1.6326x over previous
//
#include <hip/hip_runtime.h>
#include <math.h>

#define S 512
#define D 1024
#define H 16
#define DH 64
#define L 2
#define DN 512
#define DE 256
#define KTOP 3
#define E (S*KTOP)
#define D3 (3*D)
#define DFF (4*D)
#define EK (2*D+1)
#define EKP 2080   // EK padded to multiple of 32

typedef __attribute__((ext_vector_type(8))) short short8;
typedef __attribute__((ext_vector_type(4))) float f32x4;

// ---------------- bf16 split helpers ----------------
__device__ __forceinline__ unsigned short bf16r(float f) {
    unsigned u = __builtin_bit_cast(unsigned, f);
    unsigned r = (u + 0x7FFFu + ((u >> 16) & 1u)) >> 16;
    return (unsigned short)r;
}
__device__ __forceinline__ float bf16tof(unsigned short h) {
    unsigned u = ((unsigned)h) << 16;
    return __builtin_bit_cast(float, u);
}

// ---------------- reduction helpers (block = 256 = 4 waves) ----------------
__device__ __forceinline__ float block_sum_256(float v, volatile float* sh) {
    int lane = threadIdx.x & 63, wid = threadIdx.x >> 6;
    #pragma unroll
    for (int o = 32; o > 0; o >>= 1) v += __shfl_down(v, o, 64);
    if (lane == 0) sh[wid] = v;
    __syncthreads();
    float r = sh[0] + sh[1] + sh[2] + sh[3];
    __syncthreads();
    return r;
}
__device__ __forceinline__ float block_max_256(float v, volatile float* sh) {
    int lane = threadIdx.x & 63, wid = threadIdx.x >> 6;
    #pragma unroll
    for (int o = 32; o > 0; o >>= 1) v = fmaxf(v, __shfl_down(v, o, 64));
    if (lane == 0) sh[wid] = v;
    __syncthreads();
    float r = fmaxf(fmaxf(sh[0], sh[1]), fmaxf(sh[2], sh[3]));
    __syncthreads();
    return r;
}

// ---------------- embedding + positional encoding ----------------
__global__ __launch_bounds__(256) void embed_kernel(
        const int* __restrict__ tok, const float* __restrict__ emb,
        const float* __restrict__ pe, float* __restrict__ x) {
    int s = blockIdx.x;
    int t = tok[s];
    for (int d = threadIdx.x; d < D; d += 256)
        x[(size_t)s*D + d] = emb[(size_t)t*D + d] + pe[(size_t)s*D + d];
}

// ===== split-N bf16 MFMA GEMM: C = A @ W^T + bias (opt. GELU) ==============
// A: [M, sA] fp32 row-major; W: [N, sW] fp32 row-major; C: [M, ldc] fp32.
// fp32 = sum of NSPLIT bf16 planes; product via MFMA terms (i+j<NSPLIT),
// smaller-order terms accumulated first. NSPLIT=3 ~ fp32-grade (~2^-25),
// NSPLIT=2 ~ 2^-18 relative — use 3 on the top-k-ranking-critical chain.
// LDS: per plane [rows][32 k] bf16; 16B chunk at slot s -> phys s^((row>>1)&3)
// giving conflict-free b128 writes and reads.
// GUARDW: per-element bounds check on W k-index (for K=2049 edge weights).
template<int BM, int BN, int WM, int WN, int GUARDW, int NSPLIT>
__global__ __launch_bounds__((BM/WM)*(BN/WN)*64) void gemm_mfma(
        const float* __restrict__ A, const float* __restrict__ W,
        const float* __restrict__ bias, float* __restrict__ C,
        int Kreal, int sA, int sW, int ldc, int act) {
    constexpr int NWAVE = (BM/WM)*(BN/WN);
    constexpr int BLK   = NWAVE*64;
    constexpr int WCOLS = BN/WN;
    constexpr int RM    = WM/16;
    constexpr int RN    = WN/16;
    constexpr int AREP  = (BM*32)/(BLK*8);
    constexpr int WREP  = (BN*32)/(BLK*8);

    __shared__ __align__(16) unsigned short Ab[NSPLIT][BM*32];
    __shared__ __align__(16) unsigned short Wb[NSPLIT][BN*32];

    const int tid  = threadIdx.x;
    const int bm   = blockIdx.y * BM;
    const int bn   = blockIdx.x * BN;
    const int wid  = tid >> 6;
    const int lane = tid & 63;
    const int wr   = wid / WCOLS;
    const int wc   = wid % WCOLS;
    const int lrow = lane & 15;
    const int lks  = lane >> 4;          // k-slot 0..3 (8 k each)

    f32x4 acc[RM][RN];
    #pragma unroll
    for (int m = 0; m < RM; m++)
        #pragma unroll
        for (int n = 0; n < RN; n++)
            #pragma unroll
            for (int r = 0; r < 4; r++) acc[m][n][r] = 0.f;

    const int Kpad = (Kreal + 31) & ~31;

    for (int k0 = 0; k0 < Kpad; k0 += 32) {
        // ---- stage A ----
        #pragma unroll
        for (int rep = 0; rep < AREP; rep++) {
            int idx  = tid + rep*BLK;
            int row  = idx >> 2;
            int ks   = idx & 3;
            float f[8];
            const float* ap = A + (size_t)(bm + row)*sA + k0 + ks*8;
            float4 v0 = *(const float4*)ap;
            float4 v1 = *(const float4*)(ap + 4);
            f[0]=v0.x; f[1]=v0.y; f[2]=v0.z; f[3]=v0.w;
            f[4]=v1.x; f[5]=v1.y; f[6]=v1.z; f[7]=v1.w;
            short8 pv[NSPLIT];
            #pragma unroll
            for (int j = 0; j < 8; j++) {
                float rcur = f[j];
                #pragma unroll
                for (int p = 0; p < NSPLIT; p++) {
                    unsigned short hb = bf16r(rcur);
                    pv[p][j] = (short)hb;
                    rcur -= bf16tof(hb);
                }
            }
            int p = ks ^ ((row >> 1) & 3);
            #pragma unroll
            for (int pl = 0; pl < NSPLIT; pl++)
                *(short8*)&Ab[pl][row*32 + p*8] = pv[pl];
        }
        // ---- stage W ----
        #pragma unroll
        for (int rep = 0; rep < WREP; rep++) {
            int idx  = tid + rep*BLK;
            int row  = idx >> 2;
            int ks   = idx & 3;
            float f[8];
            if (GUARDW) {
                #pragma unroll
                for (int j = 0; j < 8; j++) {
                    int kk = k0 + ks*8 + j;
                    f[j] = (kk < Kreal) ? W[(size_t)(bn + row)*sW + kk] : 0.f;
                }
            } else {
                const float* wp = W + (size_t)(bn + row)*sW + k0 + ks*8;
                float4 v0 = *(const float4*)wp;
                float4 v1 = *(const float4*)(wp + 4);
                f[0]=v0.x; f[1]=v0.y; f[2]=v0.z; f[3]=v0.w;
                f[4]=v1.x; f[5]=v1.y; f[6]=v1.z; f[7]=v1.w;
            }
            short8 pv[NSPLIT];
            #pragma unroll
            for (int j = 0; j < 8; j++) {
                float rcur = f[j];
                #pragma unroll
                for (int p = 0; p < NSPLIT; p++) {
                    unsigned short hb = bf16r(rcur);
                    pv[p][j] = (short)hb;
                    rcur -= bf16tof(hb);
                }
            }
            int p = ks ^ ((row >> 1) & 3);
            #pragma unroll
            for (int pl = 0; pl < NSPLIT; pl++)
                *(short8*)&Wb[pl][row*32 + p*8] = pv[pl];
        }
        __syncthreads();

        // ---- fragments + MFMA ----
        short8 af[NSPLIT][RM], bf[NSPLIT][RN];
        #pragma unroll
        for (int m = 0; m < RM; m++) {
            int r = wr*WM + m*16 + lrow;
            int p = lks ^ ((r >> 1) & 3);
            #pragma unroll
            for (int pl = 0; pl < NSPLIT; pl++)
                af[pl][m] = *(const short8*)&Ab[pl][r*32 + p*8];
        }
        #pragma unroll
        for (int n = 0; n < RN; n++) {
            int r = wc*WN + n*16 + lrow;
            int p = lks ^ ((r >> 1) & 3);
            #pragma unroll
            for (int pl = 0; pl < NSPLIT; pl++)
                bf[pl][n] = *(const short8*)&Wb[pl][r*32 + p*8];
        }
        #pragma unroll
        for (int m = 0; m < RM; m++)
            #pragma unroll
            for (int n = 0; n < RN; n++) {
                // smaller-magnitude cross terms first
                #pragma unroll
                for (int ssum = NSPLIT-1; ssum >= 0; ssum--)
                    #pragma unroll
                    for (int i = 0; i <= ssum; i++)
                        acc[m][n] = __builtin_amdgcn_mfma_f32_16x16x32_bf16(
                            af[i][m], bf[ssum-i][n], acc[m][n], 0, 0, 0);
            }
        __syncthreads();
    }

    // ---- epilogue ----
    #pragma unroll
    for (int m = 0; m < RM; m++) {
        int grow = bm + wr*WM + m*16 + (lane >> 4)*4;
        #pragma unroll
        for (int n = 0; n < RN; n++) {
            int gcol = bn + wc*WN + n*16 + (lane & 15);
            float bv = bias ? bias[gcol] : 0.f;
            #pragma unroll
            for (int r = 0; r < 4; r++) {
                float v = acc[m][n][r] + bv;
                if (act == 1)
                    v = 0.5f * v * (1.f + erff(v * 0.70710678118654752440f));
                C[(size_t)(grow + r)*ldc + gcol] = v;
            }
        }
    }
}

// ---------------- attention: scores = (q . k) / sqrt(DH) --------------------
__global__ __launch_bounds__(256) void attn_scores_kernel(
        const float* __restrict__ qkv, float* __restrict__ w) {
    int s = blockIdx.x, h = blockIdx.y;
    __shared__ float qrow[DH];
    if (threadIdx.x < DH)
        qrow[threadIdx.x] = qkv[(size_t)s*D3 + h*DH + threadIdx.x];
    __syncthreads();
    for (int t = threadIdx.x; t < S; t += 256) {
        const float* krow = &qkv[(size_t)t*D3 + D + h*DH];
        float acc = 0.f;
        #pragma unroll
        for (int d = 0; d < DH; d++) acc += qrow[d] * krow[d];
        w[((size_t)h*S + s)*S + t] = acc * 0.125f;
    }
}

// ---------------- softmax over last dim of w[h,s,:] -------------------------
__global__ __launch_bounds__(256) void softmax_kernel(float* __restrict__ w) {
    int s = blockIdx.x, h = blockIdx.y;
    float* row = w + ((size_t)h*S + s)*S;
    __shared__ float red[4];
    float lmax = -1e30f;
    for (int t = threadIdx.x; t < S; t += 256) lmax = fmaxf(lmax, row[t]);
    float m = block_max_256(lmax, red);
    float lsum = 0.f;
    for (int t = threadIdx.x; t < S; t += 256) {
        float e = expf(row[t] - m);
        row[t] = e;
        lsum += e;
    }
    float sum = block_sum_256(lsum, red);
    float inv = 1.f / sum;
    for (int t = threadIdx.x; t < S; t += 256) row[t] *= inv;
}

// ---------------- head average ------------------
__global__ __launch_bounds__(256) void avg_heads_kernel(
        const float* __restrict__ w, float* __restrict__ avg) {
    size_t idx = (size_t)blockIdx.x * 256 + threadIdx.x;
    float acc = 0.f;
    #pragma unroll
    for (int h = 0; h < H; h++) acc += w[(size_t)h*S*S + idx];
    avg[idx] = acc * (1.f / H);
}

// ---------------- PV ----------
__global__ __launch_bounds__(256) void attn_pv_kernel(
        const float* __restrict__ w, const float* __restrict__ qkv,
        float* __restrict__ out) {
    int h = blockIdx.y;
    int s = blockIdx.x * 4 + (threadIdx.x >> 6);
    int dh = threadIdx.x & 63;
    const float* wrow = &w[((size_t)h*S + s)*S];
    float acc = 0.f;
    for (int t = 0; t < S; t++)
        acc += wrow[t] * qkv[(size_t)t*D3 + 2*D + h*DH + dh];
    out[(size_t)s*D + h*DH + dh] = acc;
}

// ---------------- residual + LayerNorm ------
__global__ __launch_bounds__(256) void add_ln_kernel(
        float* __restrict__ x, const float* __restrict__ y,
        const float* __restrict__ g, const float* __restrict__ b,
        float* __restrict__ copy_out) {
    int s = blockIdx.x;
    __shared__ float buf[D];
    __shared__ float red[4];
    float lsum = 0.f;
    for (int d = threadIdx.x; d < D; d += 256) {
        float t = x[(size_t)s*D + d] + y[(size_t)s*D + d];
        buf[d] = t;
        lsum += t;
    }
    float mean = block_sum_256(lsum, red) * (1.f / D);
    float lvar = 0.f;
    for (int d = threadIdx.x; d < D; d += 256) {
        float t = buf[d] - mean;
        lvar += t * t;
    }
    float var = block_sum_256(lvar, red) * (1.f / D);
    float inv = rsqrtf(var + 1e-5f);
    for (int d = threadIdx.x; d < D; d += 256) {
        float o = (buf[d] - mean) * inv * g[d] + b[d];
        x[(size_t)s*D + d] = o;
        if (copy_out) copy_out[(size_t)s*D + d] = o;
    }
}

// ---------------- top-K (strict > == jax.lax.top_k tie-break) ---------------
__global__ __launch_bounds__(256) void topk_kernel(
        const float* __restrict__ avg_last, int* __restrict__ tgt,
        float* __restrict__ eidx_out) {
    int s = blockIdx.x * blockDim.x + threadIdx.x;
    if (s >= S) return;
    const float* row = avg_last + (size_t)s*S;
    float v0 = -1e30f, v1 = -1e30f, v2 = -1e30f;
    int i0 = 0, i1 = 0, i2 = 0;
    for (int t = 0; t < S; t++) {
        float v = (t == s) ? 0.f : row[t];
        if (v > v0)      { v2=v1; i2=i1; v1=v0; i1=i0; v0=v; i0=t; }
        else if (v > v1) { v2=v1; i2=i1; v1=v;  i1=t; }
        else if (v > v2) { v2=v;  i2=t; }
    }
    tgt[s*KTOP + 0] = i0; tgt[s*KTOP + 1] = i1; tgt[s*KTOP + 2] = i2;
    int idx[3] = {i0, i1, i2};
    for (int k = 0; k < KTOP; k++) {
        eidx_out[s*KTOP + k]      = (float)s;
        eidx_out[E + s*KTOP + k]  = (float)idx[k];
    }
}

// ---------------- edge_in = [e[src], e[tgt], attn[src,tgt], 0-pad] ----------
__global__ __launch_bounds__(256) void build_edge_in_kernel(
        const float* __restrict__ lo, const float* __restrict__ avg,
        const int* __restrict__ tgt, float* __restrict__ edge_in) {
    int e = blockIdx.x;
    int sn = e / KTOP;
    int tn = tgt[e];
    float a = avg[(size_t)sn*S + tn];
    for (int d = threadIdx.x; d < EKP; d += 256) {
        float v;
        if (d < D)          v = lo[(size_t)sn*D + d];
        else if (d < 2*D)   v = lo[(size_t)tn*D + (d - D)];
        else if (d == 2*D)  v = a;
        else                v = 0.f;   // pad
        edge_in[(size_t)e*EKP + d] = v;
    }
}

extern "C" void kernel_launch(void* const* d_in, const int* in_sizes, int n_in,
                              void* d_out, int out_size, void* d_ws, size_t ws_size,
                              hipStream_t stream) {
    const int*   token_ids = (const int*)  d_in[0];
    const float* emb       = (const float*)d_in[1];
    const float* pe        = (const float*)d_in[2];
    const float* in_proj_w = (const float*)d_in[3];
    const float* in_proj_b = (const float*)d_in[4];
    const float* out_w     = (const float*)d_in[5];
    const float* out_b     = (const float*)d_in[6];
    const float* ln1_w     = (const float*)d_in[7];
    const float* ln1_b     = (const float*)d_in[8];
    const float* ln2_w     = (const float*)d_in[9];
    const float* ln2_b     = (const float*)d_in[10];
    const float* ff1_w     = (const float*)d_in[11];
    const float* ff1_b     = (const float*)d_in[12];
    const float* ff2_w     = (const float*)d_in[13];
    const float* ff2_b     = (const float*)d_in[14];
    const float* node_w    = (const float*)d_in[15];
    const float* node_b    = (const float*)d_in[16];
    const float* edge_w    = (const float*)d_in[17];
    const float* edge_b    = (const float*)d_in[18];
    const float* comb_w    = (const float*)d_in[19];
    const float* comb_b    = (const float*)d_in[20];

    float* out = (float*)d_out;
    float* node_out = out;                       // [S, DN]
    float* edge_out = out + (size_t)S*DN;        // [E, DE]
    float* eidx_out = edge_out + (size_t)E*DE;   // [2, E] as floats

    float* ws = (float*)d_ws;
    size_t off = 0;
    float* x       = ws + off; off += (size_t)S*D;
    float* qkv     = ws + off; off += (size_t)S*D3;
    float* wfull   = ws + off; off += (size_t)H*S*S;
    float* avg     = ws + off; off += (size_t)L*S*S;
    float* lo      = ws + off; off += (size_t)L*S*D;
    float* att     = ws + off; off += (size_t)S*D;
    float* ff      = ws + off; off += (size_t)S*DFF;
    float* tmp     = ws + off; off += (size_t)S*D;
    float* edge_in = ws + off; off += (size_t)E*EKP;
    float* feats   = ws + off; off += (size_t)E*(L*DE);
    int*   tgt     = (int*)(ws + off);

    dim3 blk(256);

    embed_kernel<<<S, blk, 0, stream>>>(token_ids, emb, pe, x);

    for (int i = 0; i < L; i++) {
        // qkv = x @ in_proj_w[i]^T + b : M=512 N=3072 K=1024 — ranking chain: split-3
        gemm_mfma<64,128,32,64,0,3><<<dim3(D3/128, S/64), dim3(256), 0, stream>>>(
            x, in_proj_w + (size_t)i*D3*D, in_proj_b + (size_t)i*D3,
            qkv, D, D, D, D3, 0);
        attn_scores_kernel<<<dim3(S, H), blk, 0, stream>>>(qkv, wfull);
        softmax_kernel<<<dim3(S, H), blk, 0, stream>>>(wfull);
        avg_heads_kernel<<<dim3(S*S/256), blk, 0, stream>>>(wfull, avg + (size_t)i*S*S);
        attn_pv_kernel<<<dim3(S/4, H), blk, 0, stream>>>(wfull, qkv, att);
        if (i == 0) {
            // layer-0 out/ff feed layer-1 logits -> split-3
            gemm_mfma<32,64,16,64,0,3><<<dim3(D/64, S/32), dim3(128), 0, stream>>>(
                att, out_w + (size_t)i*D*D, out_b + (size_t)i*D, tmp, D, D, D, D, 0);
            add_ln_kernel<<<S, blk, 0, stream>>>(
                x, tmp, ln1_w + (size_t)i*D, ln1_b + (size_t)i*D, nullptr);
            gemm_mfma<64,128,32,64,0,3><<<dim3(DFF/128, S/64), dim3(256), 0, stream>>>(
                x, ff1_w + (size_t)i*DFF*D, ff1_b + (size_t)i*DFF, ff, D, D, D, DFF, 1);
            gemm_mfma<32,64,16,64,0,3><<<dim3(D/64, S/32), dim3(128), 0, stream>>>(
                ff, ff2_w + (size_t)i*D*DFF, ff2_b + (size_t)i*D, tmp, DFF, DFF, DFF, D, 0);
        } else {
            // layer-1 out/ff only affect value outputs (lenient) -> split-2
            gemm_mfma<32,64,16,64,0,2><<<dim3(D/64, S/32), dim3(128), 0, stream>>>(
                att, out_w + (size_t)i*D*D, out_b + (size_t)i*D, tmp, D, D, D, D, 0);
            add_ln_kernel<<<S, blk, 0, stream>>>(
                x, tmp, ln1_w + (size_t)i*D, ln1_b + (size_t)i*D, nullptr);
            gemm_mfma<64,128,32,64,0,2><<<dim3(DFF/128, S/64), dim3(256), 0, stream>>>(
                x, ff1_w + (size_t)i*DFF*D, ff1_b + (size_t)i*DFF, ff, D, D, D, DFF, 1);
            gemm_mfma<32,64,16,64,0,2><<<dim3(D/64, S/32), dim3(128), 0, stream>>>(
                ff, ff2_w + (size_t)i*D*DFF, ff2_b + (size_t)i*D, tmp, DFF, DFF, DFF, D, 0);
        }
        add_ln_kernel<<<S, blk, 0, stream>>>(
            x, tmp, ln2_w + (size_t)i*D, ln2_b + (size_t)i*D, lo + (size_t)i*S*D);
    }

    // node: M=512 N=512 K=1024 (values only) — split-2
    gemm_mfma<32,64,16,64,0,2><<<dim3(DN/64, S/32), dim3(128), 0, stream>>>(
        x, node_w, node_b, node_out, D, D, D, DN, 0);

    topk_kernel<<<dim3(2), blk, 0, stream>>>(avg + (size_t)(L-1)*S*S, tgt, eidx_out);

    for (int i = 0; i < L; i++) {
        build_edge_in_kernel<<<dim3(E), blk, 0, stream>>>(
            lo + (size_t)i*S*D, avg + (size_t)i*S*S, tgt, edge_in);
        // edge MLP: M=1536 N=256 Kreal=2049 (A padded to 2080, W guarded) — split-2
        gemm_mfma<32,64,16,64,1,2><<<dim3(DE/64, E/32), dim3(128), 0, stream>>>(
            edge_in, edge_w + (size_t)i*DE*EK, edge_b + (size_t)i*DE,
            feats + (size_t)i*DE, EK, EKP, EK, L*DE, 0);
    }

    // comb: M=1536 N=256 K=512 — split-2
    gemm_mfma<32,64,16,64,0,2><<<dim3(DE/64, E/32), dim3(128), 0, stream>>>(
        feats, comb_w, comb_b, edge_out, L*DE, L*DE, L*DE, DE, 0);
}

// Round 6
// 1492.388 us; speedup vs baseline: 2.2254x; 1.3631x over previous
//
#include <hip/hip_runtime.h>
#include <math.h>

#define S 512
#define D 1024
#define H 16
#define DH 64
#define L 2
#define DN 512
#define DE 256
#define KTOP 3
#define E (S*KTOP)
#define D3 (3*D)
#define DFF (4*D)
#define EK (2*D+1)
#define EKP2 2112   // EK padded to multiple of 64

typedef __attribute__((ext_vector_type(8))) short short8;
typedef __attribute__((ext_vector_type(4))) float f32x4;

// ---------------- bf16 split helpers ----------------
__device__ __forceinline__ unsigned short bf16r(float f) {
    unsigned u = __builtin_bit_cast(unsigned, f);
    unsigned r = (u + 0x7FFFu + ((u >> 16) & 1u)) >> 16;
    return (unsigned short)r;
}
__device__ __forceinline__ float bf16tof(unsigned short h) {
    unsigned u = ((unsigned)h) << 16;
    return __builtin_bit_cast(float, u);
}
template<int NS>
__device__ __forceinline__ void split_planes(float f, unsigned short* o) {
    #pragma unroll
    for (int p = 0; p < NS; p++) {
        unsigned short h = bf16r(f);
        o[p] = h;
        f -= bf16tof(h);
    }
}

// async 16B global -> LDS (linear dest; swizzle pre-applied on global src)
__device__ __forceinline__ void gload16(unsigned short* l, const unsigned short* g) {
    __builtin_amdgcn_global_load_lds(
        (const __attribute__((address_space(1))) void*)g,
        (__attribute__((address_space(3))) void*)l,
        16, 0, 0);
}

// ---------------- reduction helpers (block = 256 = 4 waves) ----------------
__device__ __forceinline__ float block_sum_256(float v, volatile float* sh) {
    int lane = threadIdx.x & 63, wid = threadIdx.x >> 6;
    #pragma unroll
    for (int o = 32; o > 0; o >>= 1) v += __shfl_down(v, o, 64);
    if (lane == 0) sh[wid] = v;
    __syncthreads();
    float r = sh[0] + sh[1] + sh[2] + sh[3];
    __syncthreads();
    return r;
}
__device__ __forceinline__ float block_max_256(float v, volatile float* sh) {
    int lane = threadIdx.x & 63, wid = threadIdx.x >> 6;
    #pragma unroll
    for (int o = 32; o > 0; o >>= 1) v = fmaxf(v, __shfl_down(v, o, 64));
    if (lane == 0) sh[wid] = v;
    __syncthreads();
    float r = fmaxf(fmaxf(sh[0], sh[1]), fmaxf(sh[2], sh[3]));
    __syncthreads();
    return r;
}

// ---------------- weight pre-split: fp32 [N,K] -> 3 bf16 planes [N,Kpad] ----
__global__ __launch_bounds__(256) void wsplit_kernel(
        const float* __restrict__ in, unsigned short* __restrict__ out,
        int N, int K, int Kpad) {
    int nch = N * (Kpad / 8);
    size_t pstride = (size_t)N * Kpad;
    for (int c = blockIdx.x * 256 + threadIdx.x; c < nch; c += gridDim.x * 256) {
        int n = (c * 8) / Kpad, k = (c * 8) % Kpad;
        short8 pv[3];
        #pragma unroll
        for (int j = 0; j < 8; j++) {
            int kk = k + j;
            float f = (kk < K) ? in[(size_t)n*K + kk] : 0.f;
            unsigned short sp[3];
            split_planes<3>(f, sp);
            pv[0][j] = (short)sp[0]; pv[1][j] = (short)sp[1]; pv[2][j] = (short)sp[2];
        }
        #pragma unroll
        for (int pl = 0; pl < 3; pl++)
            *(short8*)&out[pl*pstride + (size_t)c*8] = pv[pl];
    }
}

// ---------------- embedding + positional encoding (+ optional planes) -------
__global__ __launch_bounds__(256) void embed_kernel(
        const int* __restrict__ tok, const float* __restrict__ emb,
        const float* __restrict__ pe, float* __restrict__ x,
        unsigned short* __restrict__ xp) {
    int s = blockIdx.x;
    int t = tok[s];
    for (int d = threadIdx.x; d < D; d += 256) {
        float v = emb[(size_t)t*D + d] + pe[(size_t)s*D + d];
        x[(size_t)s*D + d] = v;
        if (xp) {
            unsigned short sp[3];
            split_planes<3>(v, sp);
            #pragma unroll
            for (int pl = 0; pl < 3; pl++)
                xp[(size_t)pl*S*D + (size_t)s*D + d] = sp[pl];
        }
    }
}

// ===== split-N bf16 MFMA GEMM: C = A @ W^T + bias (opt. GELU) ==============
// PRE=1: A/W read from pre-split bf16 planes (plane strides psA/psW),
//        staged via global_load_lds with pre-swizzled source.
// PRE=0: A/W fp32, split in-loop (fallback when ws too small).
// LDS per plane: [row][BK] bf16; 16B chunk c of row r at phys c^((r>>1)&SWM).
// CPL>0: epilogue also writes CPL bf16 planes of the output to Cpl.
template<int BM,int BN,int WM,int WN,int BK,int NSPLIT,int PRE,int GUARDW,int CPL>
__global__ __launch_bounds__((BM/WM)*(BN/WN)*64) void gemm_mfma(
        const float* __restrict__ A, const unsigned short* __restrict__ Apl,
        const float* __restrict__ W, const unsigned short* __restrict__ Wpl,
        unsigned long long psA, unsigned long long psW,
        const float* __restrict__ bias, float* __restrict__ C,
        unsigned short* __restrict__ Cpl, unsigned long long psC,
        int Kreal, int sA, int sW, int ldc, int act) {
    constexpr int NWAVE  = (BM/WM)*(BN/WN);
    constexpr int BLK    = NWAVE*64;
    constexpr int WCOLS  = BN/WN;
    constexpr int RM     = WM/16;
    constexpr int RN     = WN/16;
    constexpr int CH     = BK/8;       // 16B chunks per row
    constexpr int SWM    = CH - 1;     // swizzle mask (3 or 7)
    constexpr int SUB    = BK/32;      // MFMA k sub-steps per stage
    constexpr int AREP   = (BM*BK)/(BLK*8);
    constexpr int WREP   = (BN*BK)/(BLK*8);
    constexpr int LOG2CH = (CH == 4) ? 2 : 3;

    __shared__ __align__(16) unsigned short Ab[NSPLIT][BM*BK];
    __shared__ __align__(16) unsigned short Wb[NSPLIT][BN*BK];

    const int tid  = threadIdx.x;
    const int bm   = blockIdx.y * BM;
    const int bn   = blockIdx.x * BN;
    const int wid  = tid >> 6;
    const int lane = tid & 63;
    const int wr   = wid / WCOLS;
    const int wc   = wid % WCOLS;
    const int lrow = lane & 15;
    const int lks  = lane >> 4;        // k-slot 0..3 (8 k each)

    f32x4 acc[RM][RN];
    #pragma unroll
    for (int m = 0; m < RM; m++)
        #pragma unroll
        for (int n = 0; n < RN; n++)
            #pragma unroll
            for (int r = 0; r < 4; r++) acc[m][n][r] = 0.f;

    const int Kpad = (Kreal + BK - 1) & ~(BK - 1);

    for (int k0 = 0; k0 < Kpad; k0 += BK) {
        if constexpr (PRE) {
            // ---- async stage pre-split planes, pre-swizzled source ----
            #pragma unroll
            for (int pl = 0; pl < NSPLIT; pl++)
                #pragma unroll
                for (int rep = 0; rep < AREP; rep++) {
                    int idx = tid + rep*BLK;
                    int row = idx >> LOG2CH, ks = idx & SWM;
                    int src = ks ^ ((row >> 1) & SWM);
                    gload16(&Ab[pl][(size_t)idx*8],
                            Apl + (size_t)pl*psA + (size_t)(bm+row)*sA + k0 + src*8);
                }
            #pragma unroll
            for (int pl = 0; pl < NSPLIT; pl++)
                #pragma unroll
                for (int rep = 0; rep < WREP; rep++) {
                    int idx = tid + rep*BLK;
                    int row = idx >> LOG2CH, ks = idx & SWM;
                    int src = ks ^ ((row >> 1) & SWM);
                    gload16(&Wb[pl][(size_t)idx*8],
                            Wpl + (size_t)pl*psW + (size_t)(bn+row)*sW + k0 + src*8);
                }
        } else {
            // ---- fp32 load + in-loop split (fallback) ----
            #pragma unroll
            for (int rep = 0; rep < AREP; rep++) {
                int idx = tid + rep*BLK;
                int row = idx >> LOG2CH, ks = idx & SWM;
                const float* ap = A + (size_t)(bm+row)*sA + k0 + ks*8;
                float4 v0 = *(const float4*)ap;
                float4 v1 = *(const float4*)(ap + 4);
                float f[8] = {v0.x,v0.y,v0.z,v0.w,v1.x,v1.y,v1.z,v1.w};
                short8 pv[NSPLIT];
                #pragma unroll
                for (int j = 0; j < 8; j++) {
                    unsigned short sp[NSPLIT];
                    split_planes<NSPLIT>(f[j], sp);
                    #pragma unroll
                    for (int pl = 0; pl < NSPLIT; pl++) pv[pl][j] = (short)sp[pl];
                }
                int p = ks ^ ((row >> 1) & SWM);
                #pragma unroll
                for (int pl = 0; pl < NSPLIT; pl++)
                    *(short8*)&Ab[pl][row*BK + p*8] = pv[pl];
            }
            #pragma unroll
            for (int rep = 0; rep < WREP; rep++) {
                int idx = tid + rep*BLK;
                int row = idx >> LOG2CH, ks = idx & SWM;
                float f[8];
                if (GUARDW) {
                    #pragma unroll
                    for (int j = 0; j < 8; j++) {
                        int kk = k0 + ks*8 + j;
                        f[j] = (kk < Kreal) ? W[(size_t)(bn+row)*sW + kk] : 0.f;
                    }
                } else {
                    const float* wp = W + (size_t)(bn+row)*sW + k0 + ks*8;
                    float4 v0 = *(const float4*)wp;
                    float4 v1 = *(const float4*)(wp + 4);
                    f[0]=v0.x;f[1]=v0.y;f[2]=v0.z;f[3]=v0.w;
                    f[4]=v1.x;f[5]=v1.y;f[6]=v1.z;f[7]=v1.w;
                }
                short8 pv[NSPLIT];
                #pragma unroll
                for (int j = 0; j < 8; j++) {
                    unsigned short sp[NSPLIT];
                    split_planes<NSPLIT>(f[j], sp);
                    #pragma unroll
                    for (int pl = 0; pl < NSPLIT; pl++) pv[pl][j] = (short)sp[pl];
                }
                int p = ks ^ ((row >> 1) & SWM);
                #pragma unroll
                for (int pl = 0; pl < NSPLIT; pl++)
                    *(short8*)&Wb[pl][row*BK + p*8] = pv[pl];
            }
        }
        __syncthreads();

        // ---- fragments + MFMA ----
        #pragma unroll
        for (int kk = 0; kk < SUB; kk++) {
            short8 af[NSPLIT][RM], bfr[NSPLIT][RN];
            #pragma unroll
            for (int m = 0; m < RM; m++) {
                int r = wr*WM + m*16 + lrow;
                int phys = (kk*4 + lks) ^ ((r >> 1) & SWM);
                #pragma unroll
                for (int pl = 0; pl < NSPLIT; pl++)
                    af[pl][m] = *(const short8*)&Ab[pl][r*BK + phys*8];
            }
            #pragma unroll
            for (int n = 0; n < RN; n++) {
                int r = wc*WN + n*16 + lrow;
                int phys = (kk*4 + lks) ^ ((r >> 1) & SWM);
                #pragma unroll
                for (int pl = 0; pl < NSPLIT; pl++)
                    bfr[pl][n] = *(const short8*)&Wb[pl][r*BK + phys*8];
            }
            #pragma unroll
            for (int m = 0; m < RM; m++)
                #pragma unroll
                for (int n = 0; n < RN; n++) {
                    #pragma unroll
                    for (int ssum = NSPLIT-1; ssum >= 0; ssum--)
                        #pragma unroll
                        for (int i = 0; i <= ssum; i++)
                            acc[m][n] = __builtin_amdgcn_mfma_f32_16x16x32_bf16(
                                af[i][m], bfr[ssum-i][n], acc[m][n], 0, 0, 0);
                }
        }
        __syncthreads();
    }

    // ---- epilogue ----
    #pragma unroll
    for (int m = 0; m < RM; m++) {
        int grow = bm + wr*WM + m*16 + (lane >> 4)*4;
        #pragma unroll
        for (int n = 0; n < RN; n++) {
            int gcol = bn + wc*WN + n*16 + (lane & 15);
            float bv = bias ? bias[gcol] : 0.f;
            #pragma unroll
            for (int r = 0; r < 4; r++) {
                float v = acc[m][n][r] + bv;
                if (act == 1)
                    v = 0.5f * v * (1.f + erff(v * 0.70710678118654752440f));
                if (C) C[(size_t)(grow + r)*ldc + gcol] = v;
                if constexpr (CPL > 0) {
                    unsigned short sp[CPL];
                    split_planes<CPL>(v, sp);
                    #pragma unroll
                    for (int pl = 0; pl < CPL; pl++)
                        Cpl[(size_t)pl*psC + (size_t)(grow + r)*ldc + gcol] = sp[pl];
                }
            }
        }
    }
}

// ---------------- attention: scores = (q . k) / sqrt(DH) --------------------
__global__ __launch_bounds__(256) void attn_scores_kernel(
        const float* __restrict__ qkv, float* __restrict__ w) {
    int s = blockIdx.x, h = blockIdx.y;
    __shared__ float qrow[DH];
    if (threadIdx.x < DH)
        qrow[threadIdx.x] = qkv[(size_t)s*D3 + h*DH + threadIdx.x];
    __syncthreads();
    for (int t = threadIdx.x; t < S; t += 256) {
        const float* krow = &qkv[(size_t)t*D3 + D + h*DH];
        float acc = 0.f;
        #pragma unroll
        for (int d = 0; d < DH; d++) acc += qrow[d] * krow[d];
        w[((size_t)h*S + s)*S + t] = acc * 0.125f;
    }
}

// ---------------- softmax over last dim of w[h,s,:] -------------------------
__global__ __launch_bounds__(256) void softmax_kernel(float* __restrict__ w) {
    int s = blockIdx.x, h = blockIdx.y;
    float* row = w + ((size_t)h*S + s)*S;
    __shared__ float red[4];
    float lmax = -1e30f;
    for (int t = threadIdx.x; t < S; t += 256) lmax = fmaxf(lmax, row[t]);
    float m = block_max_256(lmax, red);
    float lsum = 0.f;
    for (int t = threadIdx.x; t < S; t += 256) {
        float e = expf(row[t] - m);
        row[t] = e;
        lsum += e;
    }
    float sum = block_sum_256(lsum, red);
    float inv = 1.f / sum;
    for (int t = threadIdx.x; t < S; t += 256) row[t] *= inv;
}

// ---------------- head average ------------------
__global__ __launch_bounds__(256) void avg_heads_kernel(
        const float* __restrict__ w, float* __restrict__ avg) {
    size_t idx = (size_t)blockIdx.x * 256 + threadIdx.x;
    float acc = 0.f;
    #pragma unroll
    for (int h = 0; h < H; h++) acc += w[(size_t)h*S*S + idx];
    avg[idx] = acc * (1.f / H);
}

// ---------------- PV (writes fp32 and/or 3 bf16 planes) ----------
__global__ __launch_bounds__(256) void attn_pv_kernel(
        const float* __restrict__ w, const float* __restrict__ qkv,
        float* __restrict__ outf, unsigned short* __restrict__ outp) {
    int h = blockIdx.y;
    int s = blockIdx.x * 4 + (threadIdx.x >> 6);
    int dh = threadIdx.x & 63;
    const float* wrow = &w[((size_t)h*S + s)*S];
    float acc = 0.f;
    for (int t = 0; t < S; t++)
        acc += wrow[t] * qkv[(size_t)t*D3 + 2*D + h*DH + dh];
    size_t o = (size_t)s*D + h*DH + dh;
    if (outf) outf[o] = acc;
    if (outp) {
        unsigned short sp[3];
        split_planes<3>(acc, sp);
        #pragma unroll
        for (int pl = 0; pl < 3; pl++) outp[(size_t)pl*S*D + o] = sp[pl];
    }
}

// ---------------- residual + LayerNorm (+ optional planes, copy) ------
__global__ __launch_bounds__(256) void add_ln_kernel(
        float* __restrict__ x, const float* __restrict__ y,
        const float* __restrict__ g, const float* __restrict__ b,
        float* __restrict__ copy_out, unsigned short* __restrict__ xp) {
    int s = blockIdx.x;
    __shared__ float buf[D];
    __shared__ float red[4];
    float lsum = 0.f;
    for (int d = threadIdx.x; d < D; d += 256) {
        float t = x[(size_t)s*D + d] + y[(size_t)s*D + d];
        buf[d] = t;
        lsum += t;
    }
    float mean = block_sum_256(lsum, red) * (1.f / D);
    float lvar = 0.f;
    for (int d = threadIdx.x; d < D; d += 256) {
        float t = buf[d] - mean;
        lvar += t * t;
    }
    float var = block_sum_256(lvar, red) * (1.f / D);
    float inv = rsqrtf(var + 1e-5f);
    for (int d = threadIdx.x; d < D; d += 256) {
        float o = (buf[d] - mean) * inv * g[d] + b[d];
        x[(size_t)s*D + d] = o;
        if (copy_out) copy_out[(size_t)s*D + d] = o;
        if (xp) {
            unsigned short sp[3];
            split_planes<3>(o, sp);
            #pragma unroll
            for (int pl = 0; pl < 3; pl++)
                xp[(size_t)pl*S*D + (size_t)s*D + d] = sp[pl];
        }
    }
}

// ---------------- top-K (strict > == jax.lax.top_k tie-break) ---------------
__global__ __launch_bounds__(256) void topk_kernel(
        const float* __restrict__ avg_last, int* __restrict__ tgt,
        float* __restrict__ eidx_out) {
    int s = blockIdx.x * blockDim.x + threadIdx.x;
    if (s >= S) return;
    const float* row = avg_last + (size_t)s*S;
    float v0 = -1e30f, v1 = -1e30f, v2 = -1e30f;
    int i0 = 0, i1 = 0, i2 = 0;
    for (int t = 0; t < S; t++) {
        float v = (t == s) ? 0.f : row[t];
        if (v > v0)      { v2=v1; i2=i1; v1=v0; i1=i0; v0=v; i0=t; }
        else if (v > v1) { v2=v1; i2=i1; v1=v;  i1=t; }
        else if (v > v2) { v2=v;  i2=t; }
    }
    tgt[s*KTOP + 0] = i0; tgt[s*KTOP + 1] = i1; tgt[s*KTOP + 2] = i2;
    int idx[3] = {i0, i1, i2};
    for (int k = 0; k < KTOP; k++) {
        eidx_out[s*KTOP + k]      = (float)s;
        eidx_out[E + s*KTOP + k]  = (float)idx[k];
    }
}

// ------- edge_in = [e[src], e[tgt], attn, 0-pad] (fp32 and/or 2 planes) -----
__global__ __launch_bounds__(256) void build_edge_in_kernel(
        const float* __restrict__ lo, const float* __restrict__ avg,
        const int* __restrict__ tgt, float* __restrict__ ef,
        unsigned short* __restrict__ ep) {
    int e = blockIdx.x;
    int sn = e / KTOP;
    int tn = tgt[e];
    float a = avg[(size_t)sn*S + tn];
    for (int d = threadIdx.x; d < EKP2; d += 256) {
        float v;
        if (d < D)          v = lo[(size_t)sn*D + d];
        else if (d < 2*D)   v = lo[(size_t)tn*D + (d - D)];
        else if (d == 2*D)  v = a;
        else                v = 0.f;
        if (ef) ef[(size_t)e*EKP2 + d] = v;
        if (ep) {
            unsigned short sp[2];
            split_planes<2>(v, sp);
            ep[(size_t)e*EKP2 + d]                      = sp[0];
            ep[(size_t)E*EKP2 + (size_t)e*EKP2 + d]     = sp[1];
        }
    }
}

extern "C" void kernel_launch(void* const* d_in, const int* in_sizes, int n_in,
                              void* d_out, int out_size, void* d_ws, size_t ws_size,
                              hipStream_t stream) {
    const int*   token_ids = (const int*)  d_in[0];
    const float* emb       = (const float*)d_in[1];
    const float* pe        = (const float*)d_in[2];
    const float* in_proj_w = (const float*)d_in[3];
    const float* in_proj_b = (const float*)d_in[4];
    const float* out_w     = (const float*)d_in[5];
    const float* out_b     = (const float*)d_in[6];
    const float* ln1_w     = (const float*)d_in[7];
    const float* ln1_b     = (const float*)d_in[8];
    const float* ln2_w     = (const float*)d_in[9];
    const float* ln2_b     = (const float*)d_in[10];
    const float* ff1_w     = (const float*)d_in[11];
    const float* ff1_b     = (const float*)d_in[12];
    const float* ff2_w     = (const float*)d_in[13];
    const float* ff2_b     = (const float*)d_in[14];
    const float* node_w    = (const float*)d_in[15];
    const float* node_b    = (const float*)d_in[16];
    const float* edge_w    = (const float*)d_in[17];
    const float* edge_b    = (const float*)d_in[18];
    const float* comb_w    = (const float*)d_in[19];
    const float* comb_b    = (const float*)d_in[20];

    float* out = (float*)d_out;
    float* node_out = out;
    float* edge_out = out + (size_t)S*DN;
    float* eidx_out = edge_out + (size_t)E*DE;

    // ---- base fp32 region ----
    float* wsf = (float*)d_ws;
    size_t offf = 0;
    float* x     = wsf + offf; offf += (size_t)S*D;
    float* qkv   = wsf + offf; offf += (size_t)S*D3;
    float* wfull = wsf + offf; offf += (size_t)H*S*S;
    float* avg   = wsf + offf; offf += (size_t)L*S*S;
    float* lo    = wsf + offf; offf += (size_t)L*S*D;
    float* tmp   = wsf + offf; offf += (size_t)S*D;
    int*   tgt   = (int*)(wsf + offf); offf += E;   // E ints < E floats

    // ---- plane region (ushorts) ----
    unsigned short* ush = (unsigned short*)(wsf + offf);
    size_t offs = 0;
    unsigned short* inW_p   = ush + offs; offs += (size_t)L*3*D3*D;
    unsigned short* outW_p  = ush + offs; offs += (size_t)L*3*D*D;
    unsigned short* ff1W_p  = ush + offs; offs += (size_t)L*3*DFF*D;
    unsigned short* ff2W_p  = ush + offs; offs += (size_t)L*3*D*DFF;
    unsigned short* nodeW_p = ush + offs; offs += (size_t)3*DN*D;
    unsigned short* edgeW_p = ush + offs; offs += (size_t)L*3*DE*EKP2;
    unsigned short* combW_p = ush + offs; offs += (size_t)3*DE*(L*DE);
    unsigned short* x_p     = ush + offs; offs += (size_t)3*S*D;
    unsigned short* att_p   = ush + offs; offs += (size_t)3*S*D;
    unsigned short* ff_p    = ush + offs; offs += (size_t)3*S*DFF;
    unsigned short* ei_p    = ush + offs; offs += (size_t)2*E*EKP2;
    unsigned short* ft_p    = ush + offs; offs += (size_t)2*E*(L*DE);

    size_t need = offf*4 + offs*2;
    bool pre = (ws_size >= need);

    // fallback fp32 buffers (reuse plane region space)
    float* fb = wsf + offf;
    float* att_f = fb;                         // S*D
    float* ff_f  = att_f + (size_t)S*D;        // S*DFF
    float* ei_f  = ff_f + (size_t)S*DFF;       // E*EKP2
    float* ft_f  = ei_f + (size_t)E*EKP2;      // E*(L*DE)

    dim3 blk(256);

    if (pre) {
        // ---- weight pre-split (once per launch) ----
        auto wspl = [&](const float* in, unsigned short* o, int N, int K, int Kpad) {
            int nch = N * (Kpad/8);
            int grid = (nch + 255) / 256; if (grid > 1024) grid = 1024;
            wsplit_kernel<<<grid, blk, 0, stream>>>(in, o, N, K, Kpad);
        };
        for (int i = 0; i < L; i++) {
            wspl(in_proj_w + (size_t)i*D3*D, inW_p + (size_t)i*3*D3*D, D3, D, D);
            wspl(out_w    + (size_t)i*D*D,   outW_p + (size_t)i*3*D*D, D, D, D);
            wspl(ff1_w    + (size_t)i*DFF*D, ff1W_p + (size_t)i*3*DFF*D, DFF, D, D);
            wspl(ff2_w    + (size_t)i*D*DFF, ff2W_p + (size_t)i*3*D*DFF, D, DFF, DFF);
            wspl(edge_w   + (size_t)i*DE*EK, edgeW_p + (size_t)i*3*DE*EKP2, DE, EK, EKP2);
        }
        wspl(node_w, nodeW_p, DN, D, D);
        wspl(comb_w, combW_p, DE, L*DE, L*DE);

        embed_kernel<<<S, blk, 0, stream>>>(token_ids, emb, pe, x, x_p);

        for (int i = 0; i < L; i++) {
            // qkv (split-3, BK=32)
            gemm_mfma<64,128,32,64,32,3,1,0,0><<<dim3(D3/128, S/64), dim3(256), 0, stream>>>(
                nullptr, x_p, nullptr, inW_p + (size_t)i*3*D3*D,
                (size_t)S*D, (size_t)D3*D,
                in_proj_b + (size_t)i*D3, qkv, nullptr, 0, D, D, D, D3, 0);
            attn_scores_kernel<<<dim3(S, H), blk, 0, stream>>>(qkv, wfull);
            softmax_kernel<<<dim3(S, H), blk, 0, stream>>>(wfull);
            avg_heads_kernel<<<dim3(S*S/256), blk, 0, stream>>>(wfull, avg + (size_t)i*S*S);
            attn_pv_kernel<<<dim3(S/4, H), blk, 0, stream>>>(wfull, qkv, nullptr, att_p);
            if (i == 0) {
                gemm_mfma<32,64,16,64,32,3,1,0,0><<<dim3(D/64, S/32), dim3(128), 0, stream>>>(
                    nullptr, att_p, nullptr, outW_p + (size_t)i*3*D*D,
                    (size_t)S*D, (size_t)D*D,
                    out_b + (size_t)i*D, tmp, nullptr, 0, D, D, D, D, 0);
            } else {
                gemm_mfma<32,64,16,64,64,2,1,0,0><<<dim3(D/64, S/32), dim3(128), 0, stream>>>(
                    nullptr, att_p, nullptr, outW_p + (size_t)i*3*D*D,
                    (size_t)S*D, (size_t)D*D,
                    out_b + (size_t)i*D, tmp, nullptr, 0, D, D, D, D, 0);
            }
            add_ln_kernel<<<S, blk, 0, stream>>>(
                x, tmp, ln1_w + (size_t)i*D, ln1_b + (size_t)i*D, nullptr, x_p);
            if (i == 0) {
                gemm_mfma<64,128,32,64,32,3,1,0,3><<<dim3(DFF/128, S/64), dim3(256), 0, stream>>>(
                    nullptr, x_p, nullptr, ff1W_p + (size_t)i*3*DFF*D,
                    (size_t)S*D, (size_t)DFF*D,
                    ff1_b + (size_t)i*DFF, nullptr, ff_p, (size_t)S*DFF, D, D, D, DFF, 1);
                gemm_mfma<32,64,16,64,32,3,1,0,0><<<dim3(D/64, S/32), dim3(128), 0, stream>>>(
                    nullptr, ff_p, nullptr, ff2W_p + (size_t)i*3*D*DFF,
                    (size_t)S*DFF, (size_t)D*DFF,
                    ff2_b + (size_t)i*D, tmp, nullptr, 0, DFF, DFF, DFF, D, 0);
            } else {
                gemm_mfma<64,128,32,64,64,2,1,0,2><<<dim3(DFF/128, S/64), dim3(256), 0, stream>>>(
                    nullptr, x_p, nullptr, ff1W_p + (size_t)i*3*DFF*D,
                    (size_t)S*D, (size_t)DFF*D,
                    ff1_b + (size_t)i*DFF, nullptr, ff_p, (size_t)S*DFF, D, D, D, DFF, 1);
                gemm_mfma<32,64,16,64,64,2,1,0,0><<<dim3(D/64, S/32), dim3(128), 0, stream>>>(
                    nullptr, ff_p, nullptr, ff2W_p + (size_t)i*3*D*DFF,
                    (size_t)S*DFF, (size_t)D*DFF,
                    ff2_b + (size_t)i*D, tmp, nullptr, 0, DFF, DFF, DFF, D, 0);
            }
            add_ln_kernel<<<S, blk, 0, stream>>>(
                x, tmp, ln2_w + (size_t)i*D, ln2_b + (size_t)i*D, lo + (size_t)i*S*D, x_p);
        }

        gemm_mfma<32,64,16,64,64,2,1,0,0><<<dim3(DN/64, S/32), dim3(128), 0, stream>>>(
            nullptr, x_p, nullptr, nodeW_p, (size_t)S*D, (size_t)DN*D,
            node_b, node_out, nullptr, 0, D, D, D, DN, 0);

        topk_kernel<<<dim3(2), blk, 0, stream>>>(avg + (size_t)(L-1)*S*S, tgt, eidx_out);

        for (int i = 0; i < L; i++) {
            build_edge_in_kernel<<<dim3(E), blk, 0, stream>>>(
                lo + (size_t)i*S*D, avg + (size_t)i*S*S, tgt, nullptr, ei_p);
            gemm_mfma<32,64,16,64,64,2,1,0,2><<<dim3(DE/64, E/32), dim3(128), 0, stream>>>(
                nullptr, ei_p, nullptr, edgeW_p + (size_t)i*3*DE*EKP2,
                (size_t)E*EKP2, (size_t)DE*EKP2,
                edge_b + (size_t)i*DE, nullptr, ft_p + (size_t)i*DE, (size_t)E*(L*DE),
                EKP2, EKP2, EKP2, L*DE, 0);
        }

        gemm_mfma<32,64,16,64,64,2,1,0,0><<<dim3(DE/64, E/32), dim3(128), 0, stream>>>(
            nullptr, ft_p, nullptr, combW_p, (size_t)E*(L*DE), (size_t)DE*(L*DE),
            comb_b, edge_out, nullptr, 0, L*DE, L*DE, L*DE, DE, 0);
    } else {
        // ---------------- fallback: in-loop split (R3-equivalent) ----------------
        embed_kernel<<<S, blk, 0, stream>>>(token_ids, emb, pe, x, nullptr);
        for (int i = 0; i < L; i++) {
            gemm_mfma<64,128,32,64,32,3,0,0,0><<<dim3(D3/128, S/64), dim3(256), 0, stream>>>(
                x, nullptr, in_proj_w + (size_t)i*D3*D, nullptr, 0, 0,
                in_proj_b + (size_t)i*D3, qkv, nullptr, 0, D, D, D, D3, 0);
            attn_scores_kernel<<<dim3(S, H), blk, 0, stream>>>(qkv, wfull);
            softmax_kernel<<<dim3(S, H), blk, 0, stream>>>(wfull);
            avg_heads_kernel<<<dim3(S*S/256), blk, 0, stream>>>(wfull, avg + (size_t)i*S*S);
            attn_pv_kernel<<<dim3(S/4, H), blk, 0, stream>>>(wfull, qkv, att_f, nullptr);
            if (i == 0) {
                gemm_mfma<32,64,16,64,32,3,0,0,0><<<dim3(D/64, S/32), dim3(128), 0, stream>>>(
                    att_f, nullptr, out_w + (size_t)i*D*D, nullptr, 0, 0,
                    out_b + (size_t)i*D, tmp, nullptr, 0, D, D, D, D, 0);
            } else {
                gemm_mfma<32,64,16,64,64,2,0,0,0><<<dim3(D/64, S/32), dim3(128), 0, stream>>>(
                    att_f, nullptr, out_w + (size_t)i*D*D, nullptr, 0, 0,
                    out_b + (size_t)i*D, tmp, nullptr, 0, D, D, D, D, 0);
            }
            add_ln_kernel<<<S, blk, 0, stream>>>(
                x, tmp, ln1_w + (size_t)i*D, ln1_b + (size_t)i*D, nullptr, nullptr);
            if (i == 0) {
                gemm_mfma<64,128,32,64,32,3,0,0,0><<<dim3(DFF/128, S/64), dim3(256), 0, stream>>>(
                    x, nullptr, ff1_w + (size_t)i*DFF*D, nullptr, 0, 0,
                    ff1_b + (size_t)i*DFF, ff_f, nullptr, 0, D, D, D, DFF, 1);
                gemm_mfma<32,64,16,64,32,3,0,0,0><<<dim3(D/64, S/32), dim3(128), 0, stream>>>(
                    ff_f, nullptr, ff2_w + (size_t)i*D*DFF, nullptr, 0, 0,
                    ff2_b + (size_t)i*D, tmp, nullptr, 0, DFF, DFF, DFF, D, 0);
            } else {
                gemm_mfma<64,128,32,64,64,2,0,0,0><<<dim3(DFF/128, S/64), dim3(256), 0, stream>>>(
                    x, nullptr, ff1_w + (size_t)i*DFF*D, nullptr, 0, 0,
                    ff1_b + (size_t)i*DFF, ff_f, nullptr, 0, D, D, D, DFF, 1);
                gemm_mfma<32,64,16,64,64,2,0,0,0><<<dim3(D/64, S/32), dim3(128), 0, stream>>>(
                    ff_f, nullptr, ff2_w + (size_t)i*D*DFF, nullptr, 0, 0,
                    ff2_b + (size_t)i*D, tmp, nullptr, 0, DFF, DFF, DFF, D, 0);
            }
            add_ln_kernel<<<S, blk, 0, stream>>>(
                x, tmp, ln2_w + (size_t)i*D, ln2_b + (size_t)i*D, lo + (size_t)i*S*D, nullptr);
        }
        gemm_mfma<32,64,16,64,64,2,0,0,0><<<dim3(DN/64, S/32), dim3(128), 0, stream>>>(
            x, nullptr, node_w, nullptr, 0, 0, node_b, node_out, nullptr, 0, D, D, D, DN, 0);
        topk_kernel<<<dim3(2), blk, 0, stream>>>(avg + (size_t)(L-1)*S*S, tgt, eidx_out);
        for (int i = 0; i < L; i++) {
            build_edge_in_kernel<<<dim3(E), blk, 0, stream>>>(
                lo + (size_t)i*S*D, avg + (size_t)i*S*S, tgt, ei_f, nullptr);
            gemm_mfma<32,64,16,64,64,2,0,1,0><<<dim3(DE/64, E/32), dim3(128), 0, stream>>>(
                ei_f, nullptr, edge_w + (size_t)i*DE*EK, nullptr, 0, 0,
                edge_b + (size_t)i*DE, ft_f + (size_t)i*DE, nullptr, 0,
                EK, EKP2, EK, L*DE, 0);
        }
        gemm_mfma<32,64,16,64,64,2,0,0,0><<<dim3(DE/64, E/32), dim3(128), 0, stream>>>(
            ft_f, nullptr, comb_w, nullptr, 0, 0, comb_b, edge_out, nullptr, 0,
            L*DE, L*DE, L*DE, DE, 0);
    }
}